// Round 6
// baseline (891.128 us; speedup 1.0000x reference)
//
#include <hip/hip_runtime.h>
#include <math.h>

#define B 64
#define N 4096
#define D 128
#define E 512
#define CHUNKS 64
#define ROWS_PER_BLOCK (N / CHUNKS)            // 64
#define WAVES 4
#define TILE 16                                // rows per wave (single tile)
#define P (CHUNKS * WAVES)                     // 256 partials per batch
#define NEG_BIG -1e30f
#define RSTRIDE 34                             // float2 per LDS row (32 + 2 pad)

// Wave-synchronous LDS fence: drain DS pipe + compiler memory barrier.
#define LDS_FENCE() asm volatile("s_waitcnt lgkmcnt(0)" ::: "memory")

// K0: proj_q[b,d] = dot(vecQuestions[b,:], Wq[d,:]) + bq[d]; WPQ = proj_q * Wa.
// Also zeroes the per-batch completion counters for K1's fused merge.
__global__ __launch_bounds__(128) void proj_kernel(
    const float* __restrict__ vq, const float* __restrict__ Wq,
    const float* __restrict__ bq, const float* __restrict__ Wa,
    float* __restrict__ PQ, float* __restrict__ WPQ, int* __restrict__ done)
{
    int b = blockIdx.x;
    if (blockIdx.y == 0 && threadIdx.x == 0) done[b] = 0;
    int d = blockIdx.y * 64 + (threadIdx.x >> 1);
    int eh = threadIdx.x & 1;
    const float4* w = (const float4*)(Wq + (size_t)d * E + eh * (E / 2));
    const float4* v = (const float4*)(vq + (size_t)b * E + eh * (E / 2));
    float s = 0.f;
    #pragma unroll 8
    for (int i = 0; i < E / 8; ++i) {
        float4 a = w[i], x = v[i];
        s += a.x * x.x + a.y * x.y + a.z * x.z + a.w * x.w;
    }
    s += __shfl_xor(s, 1);
    if (eh == 0) {
        float pq = s + bq[d];
        PQ[b * D + d] = pq;
        WPQ[b * D + d] = pq * Wa[d];
    }
}

// K1: fixed-shift softmax partials (single 16-row tile per wave, masked-row
// load skipping) + fused last-block-per-batch merge (threadfence reduction).
__global__ __launch_bounds__(256) void att_partial_kernel(
    const float* __restrict__ kb, const int* __restrict__ cnt,
    const float* __restrict__ PQ, const float* __restrict__ WPQ,
    const float* __restrict__ ba,
    float* __restrict__ Lout, float* __restrict__ ACC,
    int* __restrict__ done, float* __restrict__ out)
{
    __shared__ float2 sP[WAVES][TILE * RSTRIDE];
    __shared__ float sNum[256];
    __shared__ int sLast;

    int blk = blockIdx.x;
    int b = blk >> 6, c = blk & (CHUNKS - 1);
    int wave = threadIdx.x >> 6, lane = threadIdx.x & 63;
    int half = lane >> 5;          // which row of each 2-row load group
    int l5 = lane & 31;            // d-quad index (d = l5*4 .. l5*4+3)
    int rq_r = lane >> 2;          // phase-B: row this lane reduces (0..15)
    int rq_q = lane & 3;           // phase-B: quarter of the row

    int limit = cnt[b];
    int eff = (limit == 0) ? N : limit;    // cnt==0 -> uniform softmax over all N
    int nwave = c * ROWS_PER_BLOCK + wave * TILE;
    int pid = b * P + c * WAVES + wave;

    float l = 0.f;
    float4 acc = {0.f, 0.f, 0.f, 0.f};

    if (nwave < eff) {                     // wave has at least one active row
        float4 pq  = *(const float4*)(PQ  + b * D + l5 * 4);
        float4 wpq = *(const float4*)(WPQ + b * D + l5 * 4);
        float bav = ba[0];
        float K = bav + 2.0f;              // fixed shift: |raw-ba| <= ||Wa||2 ~ 1.3

        const float* lbase = kb + (size_t)b * N * D + (size_t)nwave * D
                           + half * D + l5 * 4;
        float4 kv[8];
        #pragma unroll
        for (int j = 0; j < 8; ++j)
            kv[j] = *(const float4*)(lbase + (size_t)(2 * j) * D);

        // phase A: per-lane partials (s1 = kb.(pq*Wa), s2 part of ||kb*pq||^2)
        #pragma unroll
        for (int j = 0; j < 8; ++j) {
            float4 k4 = kv[j];
            float s1 = k4.x * wpq.x + k4.y * wpq.y + k4.z * wpq.z + k4.w * wpq.w;
            float ax = k4.x * pq.x, ay = k4.y * pq.y, az = k4.z * pq.z, aw = k4.w * pq.w;
            float s2 = ax * ax + ay * ay + az * az + aw * aw;
            sP[wave][(2 * j + half) * RSTRIDE + l5] = make_float2(s1, s2);
        }
        LDS_FENCE();

        // phase B: transpose-read, reduce, fixed-shift exp
        const float2* rowp = &sP[wave][rq_r * RSTRIDE + rq_q * 8];
        float4 a0 = ((const float4*)rowp)[0];
        float4 a1 = ((const float4*)rowp)[1];
        float4 a2 = ((const float4*)rowp)[2];
        float4 a3 = ((const float4*)rowp)[3];
        float t1 = ((a0.x + a0.z) + (a1.x + a1.z)) + ((a2.x + a2.z) + (a3.x + a3.z));
        float t2 = ((a0.y + a0.w) + (a1.y + a1.w)) + ((a2.y + a2.w) + (a3.y + a3.w));
        t1 += __shfl_xor(t1, 1); t2 += __shfl_xor(t2, 1);
        t1 += __shfl_xor(t1, 2); t2 += __shfl_xor(t2, 2);

        int n = nwave + rq_r;
        float inv = __builtin_amdgcn_rsqf(fmaxf(t2, 1e-24f));
        float raw = t1 * inv + bav;
        raw = (n >= limit) ? NEG_BIG : raw;   // exp underflows to exact 0
        if (limit == 0) raw = K;              // all-masked: uniform softmax
        float p = __expf(raw - K);

        l = p;
        #pragma unroll
        for (int j = 0; j < 8; ++j) {
            float pj = __shfl(p, 8 * j + 4 * half);  // p of row 2j+half
            acc.x += pj * kv[j].x; acc.y += pj * kv[j].y;
            acc.z += pj * kv[j].z; acc.w += pj * kv[j].w;
        }
    }

    // row p lives identically in 4 lanes; xor 4,8,16,32 sums the 16 rows.
    l += __shfl_xor(l, 4);
    l += __shfl_xor(l, 8);
    l += __shfl_xor(l, 16);
    l += __shfl_xor(l, 32);
    // combine the two half-row accumulator sets
    acc.x += __shfl_xor(acc.x, 32);
    acc.y += __shfl_xor(acc.y, 32);
    acc.z += __shfl_xor(acc.z, 32);
    acc.w += __shfl_xor(acc.w, 32);

    if (lane == 0) Lout[pid] = l;
    if (half == 0)
        *(float4*)(ACC + (size_t)pid * D + l5 * 4) = acc;

    // ---- fused merge: last block of this batch combines all P partials ----
    __threadfence();                       // release our partial stores
    __syncthreads();                       // all threads' stores+fences done
    if (threadIdx.x == 0)
        sLast = (__hip_atomic_fetch_add(&done[b], 1, __ATOMIC_ACQ_REL,
                                        __HIP_MEMORY_SCOPE_AGENT) == CHUNKS - 1);
    __syncthreads();
    if (!sLast) return;

    __threadfence();                       // acquire: see other blocks' stores
    int t = threadIdx.x;
    int d = t & (D - 1), hh = t >> 7;      // 2 threads per d, each sums P/2
    float lsum = 0.f;
    const float* Lb = Lout + b * P;
    #pragma unroll 8
    for (int i = 0; i < P; ++i) lsum += Lb[i];   // uniform -> scalar loads
    float num = 0.f;
    const float* accb = ACC + (size_t)b * P * D + (size_t)hh * (P / 2) * D + d;
    #pragma unroll 8
    for (int i = 0; i < P / 2; ++i) num += accb[(size_t)i * D];
    sNum[t] = num;
    __syncthreads();
    if (t < D)
        out[b * D + t] = (sNum[t] + sNum[t + D]) / lsum;
}

extern "C" void kernel_launch(void* const* d_in, const int* in_sizes, int n_in,
                              void* d_out, int out_size, void* d_ws, size_t ws_size,
                              hipStream_t stream) {
    const float* kb  = (const float*)d_in[0];
    const float* vq  = (const float*)d_in[1];
    const int*   cnt = (const int*)d_in[2];
    const float* Wq  = (const float*)d_in[3];
    const float* bq  = (const float*)d_in[4];
    const float* Wa  = (const float*)d_in[5];
    const float* ba  = (const float*)d_in[6];
    float* out = (float*)d_out;

    float* ws = (float*)d_ws;
    float* PQ  = ws;                  // B*D
    float* WPQ = PQ + B * D;          // B*D
    float* L   = WPQ + B * D;         // B*P
    float* ACC = L + B * P;           // B*P*D
    int*  done = (int*)(ACC + (size_t)B * P * D);  // B counters

    proj_kernel<<<dim3(B, 2), 128, 0, stream>>>(vq, Wq, bq, Wa, PQ, WPQ, done);
    att_partial_kernel<<<B * CHUNKS, 256, 0, stream>>>(kb, cnt, PQ, WPQ, ba,
                                                       L, ACC, done, out);
}

// Round 7
// 209.143 us; speedup vs baseline: 4.2609x; 4.2609x over previous
//
#include <hip/hip_runtime.h>
#include <math.h>

#define B 64
#define N 4096
#define D 128
#define E 512
#define CHUNKS 64
#define ROWS_PER_BLOCK (N / CHUNKS)            // 64
#define WAVES 4
#define TILE 16                                // rows per wave (single tile)
#define P (CHUNKS * WAVES)                     // 256 partials per batch
#define NEG_BIG -1e30f
#define RSTRIDE 34                             // float2 per LDS row (32 + 2 pad)

// Wave-synchronous LDS fence: drain DS pipe + compiler memory barrier.
#define LDS_FENCE() asm volatile("s_waitcnt lgkmcnt(0)" ::: "memory")

// K0: proj_q[b,d] = dot(vecQuestions[b,:], Wq[d,:]) + bq[d]; WPQ = proj_q * Wa.
__global__ __launch_bounds__(128) void proj_kernel(
    const float* __restrict__ vq, const float* __restrict__ Wq,
    const float* __restrict__ bq, const float* __restrict__ Wa,
    float* __restrict__ PQ, float* __restrict__ WPQ)
{
    int b = blockIdx.x;
    int d = blockIdx.y * 64 + (threadIdx.x >> 1);
    int eh = threadIdx.x & 1;
    const float4* w = (const float4*)(Wq + (size_t)d * E + eh * (E / 2));
    const float4* v = (const float4*)(vq + (size_t)b * E + eh * (E / 2));
    float s = 0.f;
    #pragma unroll 8
    for (int i = 0; i < E / 8; ++i) {
        float4 a = w[i], x = v[i];
        s += a.x * x.x + a.y * x.y + a.z * x.z + a.w * x.w;
    }
    s += __shfl_xor(s, 1);
    if (eh == 0) {
        float pq = s + bq[d];
        PQ[b * D + d] = pq;
        WPQ[b * D + d] = pq * Wa[d];
    }
}

// K1: fixed-shift softmax partials; single 16-row tile per wave; masked-row
// load skipping. NO cross-block fences (R6 lesson: per-block device-scope
// fences force L2 writebacks on gfx950 -> 3.5x regression). Partials are
// made visible by the kernel boundary instead.
__global__ __launch_bounds__(256) void att_partial_kernel(
    const float* __restrict__ kb, const int* __restrict__ cnt,
    const float* __restrict__ PQ, const float* __restrict__ WPQ,
    const float* __restrict__ ba,
    float* __restrict__ Lout, float* __restrict__ ACC)
{
    __shared__ float2 sP[WAVES][TILE * RSTRIDE];

    int blk = blockIdx.x;
    int b = blk >> 6, c = blk & (CHUNKS - 1);
    int wave = threadIdx.x >> 6, lane = threadIdx.x & 63;
    int half = lane >> 5;          // which row of each 2-row load group
    int l5 = lane & 31;            // d-quad index (d = l5*4 .. l5*4+3)
    int rq_r = lane >> 2;          // phase-B: row this lane reduces (0..15)
    int rq_q = lane & 3;           // phase-B: quarter of the row

    int limit = cnt[b];
    int eff = (limit == 0) ? N : limit;    // cnt==0 -> uniform softmax over all N
    int nwave = c * ROWS_PER_BLOCK + wave * TILE;
    int pid = b * P + c * WAVES + wave;

    float l = 0.f;
    float4 acc = {0.f, 0.f, 0.f, 0.f};

    if (nwave < eff) {                     // wave has at least one active row
        float4 pq  = *(const float4*)(PQ  + b * D + l5 * 4);
        float4 wpq = *(const float4*)(WPQ + b * D + l5 * 4);
        float bav = ba[0];
        float K = bav + 2.0f;              // fixed shift: |raw-ba| <= ||Wa||2 ~ 1.3

        const float* lbase = kb + (size_t)b * N * D + (size_t)nwave * D
                           + half * D + l5 * 4;
        float4 kv[8];
        #pragma unroll
        for (int j = 0; j < 8; ++j)
            kv[j] = *(const float4*)(lbase + (size_t)(2 * j) * D);

        // phase A: per-lane partials (s1 = kb.(pq*Wa), s2 part of ||kb*pq||^2)
        #pragma unroll
        for (int j = 0; j < 8; ++j) {
            float4 k4 = kv[j];
            float s1 = k4.x * wpq.x + k4.y * wpq.y + k4.z * wpq.z + k4.w * wpq.w;
            float ax = k4.x * pq.x, ay = k4.y * pq.y, az = k4.z * pq.z, aw = k4.w * pq.w;
            float s2 = ax * ax + ay * ay + az * az + aw * aw;
            sP[wave][(2 * j + half) * RSTRIDE + l5] = make_float2(s1, s2);
        }
        LDS_FENCE();

        // phase B: transpose-read, reduce, fixed-shift exp
        const float2* rowp = &sP[wave][rq_r * RSTRIDE + rq_q * 8];
        float4 a0 = ((const float4*)rowp)[0];
        float4 a1 = ((const float4*)rowp)[1];
        float4 a2 = ((const float4*)rowp)[2];
        float4 a3 = ((const float4*)rowp)[3];
        float t1 = ((a0.x + a0.z) + (a1.x + a1.z)) + ((a2.x + a2.z) + (a3.x + a3.z));
        float t2 = ((a0.y + a0.w) + (a1.y + a1.w)) + ((a2.y + a2.w) + (a3.y + a3.w));
        t1 += __shfl_xor(t1, 1); t2 += __shfl_xor(t2, 1);
        t1 += __shfl_xor(t1, 2); t2 += __shfl_xor(t2, 2);

        int n = nwave + rq_r;
        float inv = __builtin_amdgcn_rsqf(fmaxf(t2, 1e-24f));
        float raw = t1 * inv + bav;
        raw = (n >= limit) ? NEG_BIG : raw;   // exp underflows to exact 0
        if (limit == 0) raw = K;              // all-masked: uniform softmax
        float p = __expf(raw - K);

        l = p;
        #pragma unroll
        for (int j = 0; j < 8; ++j) {
            float pj = __shfl(p, 8 * j + 4 * half);  // p of row 2j+half
            acc.x += pj * kv[j].x; acc.y += pj * kv[j].y;
            acc.z += pj * kv[j].z; acc.w += pj * kv[j].w;
        }
    }

    // row p lives identically in 4 lanes; xor 4,8,16,32 sums the 16 rows.
    l += __shfl_xor(l, 4);
    l += __shfl_xor(l, 8);
    l += __shfl_xor(l, 16);
    l += __shfl_xor(l, 32);
    // combine the two half-row accumulator sets
    acc.x += __shfl_xor(acc.x, 32);
    acc.y += __shfl_xor(acc.y, 32);
    acc.z += __shfl_xor(acc.z, 32);
    acc.w += __shfl_xor(acc.w, 32);

    if (lane == 0) Lout[pid] = l;
    if (half == 0)
        *(float4*)(ACC + (size_t)pid * D + l5 * 4) = acc;
}

// K2: pure-add merge of P=256 partials per batch (all share the same shift K).
// 256 threads: 2 threads per d, each sums P/2 partials; combine via LDS.
__global__ __launch_bounds__(256) void merge_kernel(
    const float* __restrict__ Lv, const float* __restrict__ ACC,
    float* __restrict__ out)
{
    __shared__ float sNum[256];
    int b = blockIdx.x, t = threadIdx.x;
    int d = t & (D - 1), hh = t >> 7;
    const float* Lb = Lv + b * P;
    float lsum = 0.f;
    #pragma unroll 8
    for (int i = 0; i < P; ++i) lsum += Lb[i];     // uniform -> scalar loads
    float num = 0.f;
    const float* accb = ACC + (size_t)b * P * D + (size_t)hh * (P / 2) * D + d;
    #pragma unroll 8
    for (int i = 0; i < P / 2; ++i) num += accb[(size_t)i * D];
    sNum[t] = num;
    __syncthreads();
    if (t < D)
        out[b * D + t] = (sNum[t] + sNum[t + D]) / lsum;
}

extern "C" void kernel_launch(void* const* d_in, const int* in_sizes, int n_in,
                              void* d_out, int out_size, void* d_ws, size_t ws_size,
                              hipStream_t stream) {
    const float* kb  = (const float*)d_in[0];
    const float* vq  = (const float*)d_in[1];
    const int*   cnt = (const int*)d_in[2];
    const float* Wq  = (const float*)d_in[3];
    const float* bq  = (const float*)d_in[4];
    const float* Wa  = (const float*)d_in[5];
    const float* ba  = (const float*)d_in[6];
    float* out = (float*)d_out;

    float* ws = (float*)d_ws;
    float* PQ  = ws;                  // B*D
    float* WPQ = PQ + B * D;          // B*D
    float* L   = WPQ + B * D;         // B*P
    float* ACC = L + B * P;           // B*P*D

    proj_kernel<<<dim3(B, 2), 128, 0, stream>>>(vq, Wq, bq, Wa, PQ, WPQ);
    att_partial_kernel<<<B * CHUNKS, 256, 0, stream>>>(kb, cnt, PQ, WPQ, ba, L, ACC);
    merge_kernel<<<B, 256, 0, stream>>>(L, ACC, out);
}

// Round 8
// 198.660 us; speedup vs baseline: 4.4857x; 1.0528x over previous
//
#include <hip/hip_runtime.h>
#include <math.h>

#define B 64
#define N 4096
#define D 128
#define E 512
#define CHUNKS 32
#define ROWS_PER_BLOCK (N / CHUNKS)            // 128
#define WAVES 4
#define ROWS_PER_WAVE (ROWS_PER_BLOCK / WAVES) // 32
#define TILE 16
#define MAXTILES (ROWS_PER_WAVE / TILE)        // 2
#define NEG_BIG -1e30f
#define RSTRIDE 34                             // float2 per LDS row (32 + 2 pad)

// Wave-synchronous LDS fence: drain DS pipe + compiler memory barrier.
#define LDS_FENCE() asm volatile("s_waitcnt lgkmcnt(0)" ::: "memory")

// K0: proj_q[b,d] = dot(vecQuestions[b,:], Wq[d,:]) + bq[d]; WPQ = proj_q * Wa.
__global__ __launch_bounds__(128) void proj_kernel(
    const float* __restrict__ vq, const float* __restrict__ Wq,
    const float* __restrict__ bq, const float* __restrict__ Wa,
    float* __restrict__ PQ, float* __restrict__ WPQ)
{
    int b = blockIdx.x;
    int d = blockIdx.y * 64 + (threadIdx.x >> 1);
    int eh = threadIdx.x & 1;
    const float4* w = (const float4*)(Wq + (size_t)d * E + eh * (E / 2));
    const float4* v = (const float4*)(vq + (size_t)b * E + eh * (E / 2));
    float s = 0.f;
    #pragma unroll 8
    for (int i = 0; i < E / 8; ++i) {
        float4 a = w[i], x = v[i];
        s += a.x * x.x + a.y * x.y + a.z * x.z + a.w * x.w;
    }
    s += __shfl_xor(s, 1);
    if (eh == 0) {
        float pq = s + bq[d];
        PQ[b * D + d] = pq;
        WPQ[b * D + d] = pq * Wa[d];
    }
}

// K1: fixed-shift softmax partials (R4's 2-tile prefetch structure) +
// block-level partial combine (4 waves -> 1 partial per block via LDS).
// No cross-block fences (R6 lesson: per-block device-scope fences force L2
// writebacks on gfx950 -> 3.5x regression); kernel boundary publishes.
__global__ __launch_bounds__(256) void att_partial_kernel(
    const float* __restrict__ kb, const int* __restrict__ cnt,
    const float* __restrict__ PQ, const float* __restrict__ WPQ,
    const float* __restrict__ ba,
    float* __restrict__ Lout, float* __restrict__ ACC)
{
    __shared__ float2 sP[WAVES][TILE * RSTRIDE];
    __shared__ float4 sAcc[WAVES][32];
    __shared__ float  sL[WAVES];

    int blk = blockIdx.x;
    int b = blk >> 5, c = blk & (CHUNKS - 1);
    int wave = threadIdx.x >> 6, lane = threadIdx.x & 63;
    int half = lane >> 5;          // which row of each 2-row load group
    int l5 = lane & 31;            // d-quad index (d = l5*4 .. l5*4+3)
    int rq_r = lane >> 2;          // phase-B: row this lane reduces (0..15)
    int rq_q = lane & 3;           // phase-B: quarter of the row

    int limit = cnt[b];
    int eff = (limit == 0) ? N : limit;    // cnt==0 -> uniform softmax over all N
    int pidb = b * CHUNKS + c;             // one partial per block

    // fully-masked block: write one zeroed partial, exit before any sync
    if (c * ROWS_PER_BLOCK >= eff) {
        if (wave == 0) {
            if (lane == 0) Lout[pidb] = 0.f;
            if (half == 0)
                *(float4*)(ACC + (size_t)pidb * D + l5 * 4) =
                    make_float4(0.f, 0.f, 0.f, 0.f);
        }
        return;
    }

    int nwave = c * ROWS_PER_BLOCK + wave * ROWS_PER_WAVE;
    int wact = eff - nwave;
    int ntiles = 0;
    if (wact > 0) {
        ntiles = (wact + TILE - 1) >> 4;
        if (ntiles > MAXTILES) ntiles = MAXTILES;
    }

    float l = 0.f;
    float4 acc = {0.f, 0.f, 0.f, 0.f};

    if (ntiles > 0) {
        float4 pq  = *(const float4*)(PQ  + b * D + l5 * 4);
        float4 wpq = *(const float4*)(WPQ + b * D + l5 * 4);
        float bav = ba[0];
        float K = bav + 2.0f;      // fixed shift: |raw-ba| <= ||Wa||2 ~ 1.3

        const float* lbase = kb + (size_t)b * N * D + (size_t)nwave * D
                           + half * D + l5 * 4;
        float4 kv[8];
        #pragma unroll
        for (int j = 0; j < 8; ++j)
            kv[j] = *(const float4*)(lbase + (size_t)(2 * j) * D);

        for (int t = 0; t < ntiles; ++t) {
            // ---- phase A: per-lane partials -> LDS ----
            #pragma unroll
            for (int j = 0; j < 8; ++j) {
                float4 k4 = kv[j];
                float s1 = k4.x * wpq.x + k4.y * wpq.y + k4.z * wpq.z + k4.w * wpq.w;
                float ax = k4.x * pq.x, ay = k4.y * pq.y, az = k4.z * pq.z, aw = k4.w * pq.w;
                float s2 = ax * ax + ay * ay + az * az + aw * aw;
                sP[wave][(2 * j + half) * RSTRIDE + l5] = make_float2(s1, s2);
            }

            // issue next tile's loads BEFORE the fence: overlap with phase B
            float4 kvn[8];
            if (t + 1 < ntiles) {
                #pragma unroll
                for (int j = 0; j < 8; ++j)
                    kvn[j] = *(const float4*)(lbase + (size_t)((t + 1) * TILE + 2 * j) * D);
            }

            LDS_FENCE();

            // ---- phase B: transpose-read, reduce, fixed-shift exp ----
            const float2* rowp = &sP[wave][rq_r * RSTRIDE + rq_q * 8];
            float4 a0 = ((const float4*)rowp)[0];
            float4 a1 = ((const float4*)rowp)[1];
            float4 a2 = ((const float4*)rowp)[2];
            float4 a3 = ((const float4*)rowp)[3];
            float t1 = ((a0.x + a0.z) + (a1.x + a1.z)) + ((a2.x + a2.z) + (a3.x + a3.z));
            float t2 = ((a0.y + a0.w) + (a1.y + a1.w)) + ((a2.y + a2.w) + (a3.y + a3.w));
            t1 += __shfl_xor(t1, 1); t2 += __shfl_xor(t2, 1);
            t1 += __shfl_xor(t1, 2); t2 += __shfl_xor(t2, 2);

            int n = nwave + t * TILE + rq_r;
            float inv = __builtin_amdgcn_rsqf(fmaxf(t2, 1e-24f));
            float raw = t1 * inv + bav;
            raw = (n >= limit) ? NEG_BIG : raw;   // exp underflows to exact 0
            if (limit == 0) raw = K;              // all-masked: uniform softmax
            float p = __expf(raw - K);

            l += p;   // per-lane; reduced once at kernel end

            #pragma unroll
            for (int j = 0; j < 8; ++j) {
                float pj = __shfl(p, 8 * j + 4 * half);  // p of row 2j+half
                acc.x += pj * kv[j].x; acc.y += pj * kv[j].y;
                acc.z += pj * kv[j].z; acc.w += pj * kv[j].w;
            }

            #pragma unroll
            for (int j = 0; j < 8; ++j) kv[j] = kvn[j];
        }

        // row p lives identically in 4 lanes; xor 4,8,16,32 sums wave's rows
        l += __shfl_xor(l, 4);
        l += __shfl_xor(l, 8);
        l += __shfl_xor(l, 16);
        l += __shfl_xor(l, 32);
        // combine the two half-row accumulator sets
        acc.x += __shfl_xor(acc.x, 32);
        acc.y += __shfl_xor(acc.y, 32);
        acc.z += __shfl_xor(acc.z, 32);
        acc.w += __shfl_xor(acc.w, 32);
    }

    // ---- block-level combine: 4 wave partials -> 1 (ACC shrinks 4x) ----
    if (half == 0) sAcc[wave][l5] = acc;
    if (lane == 0) sL[wave] = l;
    __syncthreads();
    if (wave == 0) {
        if (half == 0) {
            float4 s0 = sAcc[0][l5], s1 = sAcc[1][l5],
                   s2 = sAcc[2][l5], s3 = sAcc[3][l5];
            float4 r = make_float4(s0.x + s1.x + s2.x + s3.x,
                                   s0.y + s1.y + s2.y + s3.y,
                                   s0.z + s1.z + s2.z + s3.z,
                                   s0.w + s1.w + s2.w + s3.w);
            *(float4*)(ACC + (size_t)pidb * D + l5 * 4) = r;
        }
        if (lane == 0) Lout[pidb] = sL[0] + sL[1] + sL[2] + sL[3];
    }
}

// K2: pure-add merge of CHUNKS=32 partials per batch.
__global__ __launch_bounds__(128) void merge_kernel(
    const float* __restrict__ Lv, const float* __restrict__ ACC,
    float* __restrict__ out)
{
    int b = blockIdx.x, d = threadIdx.x;
    const float* Lb = Lv + b * CHUNKS;
    float lsum = 0.f;
    #pragma unroll 8
    for (int i = 0; i < CHUNKS; ++i) lsum += Lb[i];   // uniform -> scalar loads
    float num = 0.f;
    const float* accb = ACC + (size_t)b * CHUNKS * D + d;
    #pragma unroll 8
    for (int i = 0; i < CHUNKS; ++i) num += accb[(size_t)i * D];
    out[b * D + d] = num / lsum;
}

extern "C" void kernel_launch(void* const* d_in, const int* in_sizes, int n_in,
                              void* d_out, int out_size, void* d_ws, size_t ws_size,
                              hipStream_t stream) {
    const float* kb  = (const float*)d_in[0];
    const float* vq  = (const float*)d_in[1];
    const int*   cnt = (const int*)d_in[2];
    const float* Wq  = (const float*)d_in[3];
    const float* bq  = (const float*)d_in[4];
    const float* Wa  = (const float*)d_in[5];
    const float* ba  = (const float*)d_in[6];
    float* out = (float*)d_out;

    float* ws = (float*)d_ws;
    float* PQ  = ws;                  // B*D
    float* WPQ = PQ + B * D;          // B*D
    float* L   = WPQ + B * D;         // B*CHUNKS
    float* ACC = L + B * CHUNKS;      // B*CHUNKS*D

    proj_kernel<<<dim3(B, 2), 128, 0, stream>>>(vq, Wq, bq, Wa, PQ, WPQ);
    att_partial_kernel<<<B * CHUNKS, 256, 0, stream>>>(kb, cnt, PQ, WPQ, ba, L, ACC);
    merge_kernel<<<B, 128, 0, stream>>>(L, ACC, out);
}